// Round 1
// baseline (584.929 us; speedup 1.0000x reference)
//
#include <hip/hip_runtime.h>

// out[c,i,j] = one_hot[i,c]   (c<4)   — row broadcast
// out[c,i,j] = one_hot[j,c-4] (c>=4)  — column broadcast
// L=4096, one_hot: [L,4] float32, out: [8,L,L] float32 (512 MiB, write-BW bound)

constexpr int L  = 4096;
constexpr int NB = 4;

__global__ __launch_bounds__(256) void seq_embed(const float* __restrict__ oh,
                                                 float* __restrict__ out) {
    const int row = blockIdx.x;        // 0 .. 8*L-1 : (channel, i) pair
    const int c   = row >> 12;         // row / L  (channel 0..7)
    const int i   = row & (L - 1);     // row within channel
    float4* __restrict__ orow =
        reinterpret_cast<float4*>(out) + (size_t)row * (L / 4);
    const int t = threadIdx.x;

    if (c < NB) {
        // whole row is one scalar
        const float v = oh[i * NB + c];
        const float4 v4 = make_float4(v, v, v, v);
#pragma unroll
        for (int k = 0; k < 4; ++k)
            orow[t + 256 * k] = v4;    // lane-consecutive float4 -> coalesced
    } else {
        const int cc = c - NB;
#pragma unroll
        for (int k = 0; k < 4; ++k) {
            const int j4 = t + 256 * k;   // float4 index within row
            const int j  = 4 * j4;        // element index
            float4 v;
            v.x = oh[(j + 0) * NB + cc];  // 64 KiB input: L1-resident
            v.y = oh[(j + 1) * NB + cc];
            v.z = oh[(j + 2) * NB + cc];
            v.w = oh[(j + 3) * NB + cc];
            orow[j4] = v;
        }
    }
}

extern "C" void kernel_launch(void* const* d_in, const int* in_sizes, int n_in,
                              void* d_out, int out_size, void* d_ws, size_t ws_size,
                              hipStream_t stream) {
    const float* oh = (const float*)d_in[0];
    float* out = (float*)d_out;
    seq_embed<<<8 * L, 256, 0, stream>>>(oh, out);
}